// Round 6
// baseline (371.300 us; speedup 1.0000x reference)
//
#include <hip/hip_runtime.h>
#include <hip/hip_bf16.h>

// ---------------------------------------------------------------------------
// GANClassifier forward, round 5: bf16 MFMA everywhere incl. gathered logits.
//   - 5 FFN/GAT GEMMs: mfma_f32_16x16x32_bf16, 64x64 tile, BK=64,
//     global_load_lds(16B), pre-swizzled src + swizzled ds_read (rule #21)
//   - logits: gather-MFMA (A rows indexed through input_node_indices)
//   - BatchNorm folded into bf16 weights; bf16 colstats vectorized (uint4)
//   - adjacency layout probe inlined into build_nbr
// ---------------------------------------------------------------------------

#define NNODES 4096
#define CAP 128

typedef unsigned short u16;
typedef __attribute__((ext_vector_type(8))) short bf16x8;
typedef __attribute__((ext_vector_type(4))) float f32x4;

__device__ __forceinline__ float gelu_f(float x) {
    return 0.5f * x * (1.0f + erff(x * 0.70710678118654752f));
}
__device__ __forceinline__ u16 f2bf(float x) {
    union { float f; unsigned u; } v; v.f = x;
    unsigned r = v.u + 0x7fff + ((v.u >> 16) & 1);
    return (u16)(r >> 16);
}
__device__ __forceinline__ float bf2f(u16 b) {
    return __uint_as_float(((unsigned)b) << 16);
}
__device__ __forceinline__ void gload16(const void* g, void* l) {
    __builtin_amdgcn_global_load_lds(
        (const __attribute__((address_space(1))) unsigned int*)g,
        (__attribute__((address_space(3))) unsigned int*)l, 16, 0, 0);
}

// ---------------- column stats (fp32 input, optional bf16 copy-out) --------
template<int CPT, bool CVT>
__global__ __launch_bounds__(256) void colstats_partial(
    const float* __restrict__ X, float* __restrict__ part,
    u16* __restrict__ x16, int rpb)
{
    const int C = CPT * 256;
    const int r0 = blockIdx.x * rpb;
    const int t = threadIdx.x;
    float s[CPT], q[CPT];
#pragma unroll
    for (int cc = 0; cc < CPT; ++cc) { s[cc] = 0.f; q[cc] = 0.f; }
    for (int r = 0; r < rpb; ++r) {
        const float* row = X + (size_t)(r0 + r) * C;
#pragma unroll
        for (int cc = 0; cc < CPT; ++cc) {
            float v = row[cc * 256 + t];
            s[cc] += v; q[cc] += v * v;
            if (CVT) x16[(size_t)(r0 + r) * C + cc * 256 + t] = f2bf(v);
        }
    }
#pragma unroll
    for (int cc = 0; cc < CPT; ++cc) {
        int c = cc * 256 + t;
        part[((size_t)blockIdx.x * C + c) * 2 + 0] = s[cc];
        part[((size_t)blockIdx.x * C + c) * 2 + 1] = q[cc];
    }
}

// ---------------- column stats (bf16 input, uint4-vectorized) --------------
// C = CPT*256 columns. Each thread owns 8 consecutive cols in one of
// rstep=2048/C row sub-passes; writes rstep partial slices per block.
template<int CPT>
__global__ __launch_bounds__(256) void colstats_partial_b16(
    const u16* __restrict__ X, float* __restrict__ part, int rpb)
{
    const int C = CPT * 256;
    const int CW = C / 8;            // uint4 chunks per row
    const int rstep = 256 / CW;      // row sub-passes covered per iteration
    const int t = threadIdx.x;
    const int cchunk = t % CW;
    const int rsub = t / CW;
    const int r0 = blockIdx.x * rpb;
    float s[8], q[8];
#pragma unroll
    for (int j = 0; j < 8; ++j) { s[j] = 0.f; q[j] = 0.f; }
    for (int r = rsub; r < rpb; r += rstep) {
        uint4 v = *(const uint4*)(X + (size_t)(r0 + r) * C + cchunk * 8);
        unsigned wd[4] = {v.x, v.y, v.z, v.w};
#pragma unroll
        for (int j = 0; j < 4; ++j) {
            float lo = bf2f((u16)(wd[j] & 0xffffu));
            float hi = bf2f((u16)(wd[j] >> 16));
            s[2 * j] += lo;     q[2 * j] += lo * lo;
            s[2 * j + 1] += hi; q[2 * j + 1] += hi * hi;
        }
    }
#pragma unroll
    for (int j = 0; j < 8; ++j) {
        int c = cchunk * 8 + j;
        size_t slice = (size_t)blockIdx.x * rstep + rsub;
        part[(slice * C + c) * 2 + 0] = s[j];
        part[(slice * C + c) * 2 + 1] = q[j];
    }
}

__global__ __launch_bounds__(256) void colstats_final(
    const float* __restrict__ part, const float* __restrict__ g,
    const float* __restrict__ bt, float* __restrict__ scl,
    float* __restrict__ shf, int NB, int C)
{
    int c = blockIdx.x * 256 + threadIdx.x;
    if (c >= C) return;
    float s = 0.f, q = 0.f;
    for (int b = 0; b < NB; ++b) {
        s += part[((size_t)b * C + c) * 2 + 0];
        q += part[((size_t)b * C + c) * 2 + 1];
    }
    float m = s * (1.0f / 4096.0f);
    float v = q * (1.0f / 4096.0f) - m * m;
    float sc = g[c] * rsqrtf(v + 1e-5f);
    scl[c] = sc;
    shf[c] = bt[c] - m * sc;
}

// ---------------- fold BN into weights: W16 = bf16(W*scl), b' = c + W@shf --
// rows >= nvalid are zero-padded (for the 40->64 logits pad).
__global__ __launch_bounds__(256) void foldw_kernel(
    const float* __restrict__ W, const float* __restrict__ scl,
    const float* __restrict__ shf, const float* __restrict__ bias,
    u16* __restrict__ W16, float* __restrict__ bout, int K, int nvalid)
{
    __shared__ float red[4];
    const int n = blockIdx.x, t = threadIdx.x;
    u16* o = W16 + (size_t)n * K;
    if (n >= nvalid) {
        for (int k = t; k < K; k += 256) o[k] = 0;
        if (t == 0) bout[n] = 0.f;
        return;
    }
    const float* w = W + (size_t)n * K;
    float part = 0.f;
    for (int k = t; k < K; k += 256) {
        float wv = w[k];
        float s = scl ? scl[k] : 1.f;
        float f = shf ? shf[k] : 0.f;
        o[k] = f2bf(wv * s);
        part += wv * f;
    }
    int lane = t & 63, wv_ = t >> 6;
#pragma unroll
    for (int off = 32; off > 0; off >>= 1) part += __shfl_down(part, off);
    if (lane == 0) red[wv_] = part;
    __syncthreads();
    if (t == 0)
        bout[n] = (bias ? bias[n] : 0.f) + red[0] + red[1] + red[2] + red[3];
}

// ---------------- bf16 MFMA GEMM: C = epi(A @ W^T + bias) ------------------
template<bool EPI, bool S32, bool S16>
__global__ __launch_bounds__(256) void mfma_gemm(
    const u16* __restrict__ A, const u16* __restrict__ W,
    const float* __restrict__ bias, float* __restrict__ C32,
    u16* __restrict__ C16, int M, int N, int K)
{
    __shared__ u16 As[64 * 64];
    __shared__ u16 Bs[64 * 64];
    const int t = threadIdx.x;
    const int lane = t & 63, wv = t >> 6;
    const int wm = (wv >> 1) * 32, wn = (wv & 1) * 32;
    const int tile_m = blockIdx.y * 64, tile_n = blockIdx.x * 64;

    f32x4 acc[2][2];
#pragma unroll
    for (int i = 0; i < 2; ++i)
#pragma unroll
        for (int j = 0; j < 2; ++j)
#pragma unroll
            for (int e = 0; e < 4; ++e) acc[i][j][e] = 0.f;

    int srow[2], soff[2];
#pragma unroll
    for (int i = 0; i < 2; ++i) {
        int f = i * 256 + t;
        srow[i] = f >> 3;
        soff[i] = ((f & 7) ^ (srow[i] & 7)) * 8;
    }
    char* ldsA0 = (char*)As + (t >> 6) * 1024;
    char* ldsB0 = (char*)Bs + (t >> 6) * 1024;
    const int frow_a0 = wm + (lane & 15);
    const int frow_b0 = wn + (lane & 15);
    const int fk = (lane >> 4) * 16;

    const int NT = K >> 6;
    for (int kt = 0; kt < NT; ++kt) {
#pragma unroll
        for (int i = 0; i < 2; ++i) {
            gload16(A + (size_t)(tile_m + srow[i]) * K + kt * 64 + soff[i],
                    ldsA0 + i * 4096);
            gload16(W + (size_t)(tile_n + srow[i]) * K + kt * 64 + soff[i],
                    ldsB0 + i * 4096);
        }
        __syncthreads();
#pragma unroll
        for (int kk = 0; kk < 2; ++kk) {
            bf16x8 a[2], b[2];
#pragma unroll
            for (int mi = 0; mi < 2; ++mi) {
                int r = frow_a0 + mi * 16;
                a[mi] = *(const bf16x8*)((const char*)As + r * 128 +
                        ((kk * 64 + fk) ^ ((r & 7) << 4)));
            }
#pragma unroll
            for (int ni = 0; ni < 2; ++ni) {
                int r = frow_b0 + ni * 16;
                b[ni] = *(const bf16x8*)((const char*)Bs + r * 128 +
                        ((kk * 64 + fk) ^ ((r & 7) << 4)));
            }
#pragma unroll
            for (int mi = 0; mi < 2; ++mi)
#pragma unroll
                for (int ni = 0; ni < 2; ++ni)
                    acc[mi][ni] = __builtin_amdgcn_mfma_f32_16x16x32_bf16(
                        a[mi], b[ni], acc[mi][ni], 0, 0, 0);
        }
        __syncthreads();
    }

#pragma unroll
    for (int mi = 0; mi < 2; ++mi) {
#pragma unroll
        for (int ni = 0; ni < 2; ++ni) {
            int col = tile_n + wn + ni * 16 + (lane & 15);
            float bs = 0.f;
            if (EPI) bs = bias[col];
#pragma unroll
            for (int e = 0; e < 4; ++e) {
                int row = tile_m + wm + mi * 16 + ((lane >> 4) << 2) + e;
                float c = acc[mi][ni][e];
                if (EPI) c = gelu_f(c + bs);
                if (S32) C32[(size_t)row * N + col] = c;
                if (S16) C16[(size_t)row * N + col] = f2bf(c);
            }
        }
    }
}

// ---------------- gathered logits GEMM: out = XF16[idx] @ WlP^T + cl -------
// WlP is [64][256] bf16, rows 40..63 zero. Grid: 128 blocks of 64 rows.
__global__ __launch_bounds__(256) void logits_mfma(
    const u16* __restrict__ xf16, const int* __restrict__ idxs,
    const u16* __restrict__ WlP, const float* __restrict__ clP,
    float* __restrict__ out)
{
    __shared__ u16 As[64 * 64];
    __shared__ u16 Bs[64 * 64];
    const int t = threadIdx.x;
    const int lane = t & 63, wv = t >> 6;
    const int wm = (wv >> 1) * 32, wn = (wv & 1) * 32;
    const int tile_m = blockIdx.x * 64;

    f32x4 acc[2][2];
#pragma unroll
    for (int i = 0; i < 2; ++i)
#pragma unroll
        for (int j = 0; j < 2; ++j)
#pragma unroll
            for (int e = 0; e < 4; ++e) acc[i][j][e] = 0.f;

    int srow[2], soff[2], gr[2];
#pragma unroll
    for (int i = 0; i < 2; ++i) {
        int f = i * 256 + t;
        srow[i] = f >> 3;
        soff[i] = ((f & 7) ^ (srow[i] & 7)) * 8;
        gr[i] = idxs[tile_m + srow[i]];          // row gather
    }
    char* ldsA0 = (char*)As + (t >> 6) * 1024;
    char* ldsB0 = (char*)Bs + (t >> 6) * 1024;
    const int frow_a0 = wm + (lane & 15);
    const int frow_b0 = wn + (lane & 15);
    const int fk = (lane >> 4) * 16;

#pragma unroll
    for (int kt = 0; kt < 4; ++kt) {             // K = 256
#pragma unroll
        for (int i = 0; i < 2; ++i) {
            gload16(xf16 + (size_t)gr[i] * 256 + kt * 64 + soff[i],
                    ldsA0 + i * 4096);
            gload16(WlP + (size_t)srow[i] * 256 + kt * 64 + soff[i],
                    ldsB0 + i * 4096);
        }
        __syncthreads();
#pragma unroll
        for (int kk = 0; kk < 2; ++kk) {
            bf16x8 a[2], b[2];
#pragma unroll
            for (int mi = 0; mi < 2; ++mi) {
                int r = frow_a0 + mi * 16;
                a[mi] = *(const bf16x8*)((const char*)As + r * 128 +
                        ((kk * 64 + fk) ^ ((r & 7) << 4)));
            }
#pragma unroll
            for (int ni = 0; ni < 2; ++ni) {
                int r = frow_b0 + ni * 16;
                b[ni] = *(const bf16x8*)((const char*)Bs + r * 128 +
                        ((kk * 64 + fk) ^ ((r & 7) << 4)));
            }
#pragma unroll
            for (int mi = 0; mi < 2; ++mi)
#pragma unroll
                for (int ni = 0; ni < 2; ++ni)
                    acc[mi][ni] = __builtin_amdgcn_mfma_f32_16x16x32_bf16(
                        a[mi], b[ni], acc[mi][ni], 0, 0, 0);
        }
        __syncthreads();
    }

#pragma unroll
    for (int mi = 0; mi < 2; ++mi) {
#pragma unroll
        for (int ni = 0; ni < 2; ++ni) {
            int col = wn + ni * 16 + (lane & 15);
            if (col < 40) {
                float bs = clP[col];
#pragma unroll
                for (int e = 0; e < 4; ++e) {
                    int row = tile_m + wm + mi * 16 + ((lane >> 4) << 2) + e;
                    out[(size_t)row * 40 + col] = acc[mi][ni][e] + bs;
                }
            }
        }
    }
}

// ---------------- a_src / a_tgt --------------------------------------------
__global__ __launch_bounds__(256) void asrc_atgt_kernel(
    const float* __restrict__ xh, const float* __restrict__ Wa,
    float* __restrict__ asrc, float* __restrict__ atgt)
{
    int node = (blockIdx.x * 256 + threadIdx.x) >> 6;
    int lane = threadIdx.x & 63;
    const float* row = xh + (size_t)node * 256;
    float ws = Wa[lane], wt = Wa[64 + lane];
    float s[4], tt[4];
#pragma unroll
    for (int h = 0; h < 4; ++h) {
        float v = row[h * 64 + lane];
        s[h] = v * ws; tt[h] = v * wt;
    }
#pragma unroll
    for (int off = 32; off > 0; off >>= 1) {
#pragma unroll
        for (int h = 0; h < 4; ++h) {
            s[h] += __shfl_down(s[h], off);
            tt[h] += __shfl_down(tt[h], off);
        }
    }
    if (lane == 0) {
#pragma unroll
        for (int h = 0; h < 4; ++h) {
            asrc[node * 4 + h] = s[h];
            atgt[node * 4 + h] = tt[h];
        }
    }
}

// ---------------- adjacency -> neighbor lists (block per row) --------------
// Inline layout probe (wave 0 checks the self-loop diagonal), then per-wave
// ballot compaction into LDS lists (order-agnostic), concatenated.
__global__ __launch_bounds__(256) void build_nbr_kernel(
    const unsigned char* __restrict__ adj, int* __restrict__ nbr,
    int* __restrict__ deg)
{
    __shared__ int lists[4][CAP];
    __shared__ int cnts[4];
    __shared__ int sflag;
    const int i = blockIdx.x;
    const int t = threadIdx.x;
    const int wv = t >> 6, lane = t & 63;

    if (wv == 0) {
        bool a = adj[(size_t)lane * 4097] != 0;
        bool b = ((const unsigned int*)adj)[(size_t)lane * 4097] != 0;
        unsigned long long mA = __ballot(a);
        unsigned long long mB = __ballot(b);
        if (lane == 0) sflag = (__popcll(mA) >= __popcll(mB)) ? 0 : 1;
    }
    __syncthreads();
    int cnt = 0;

    if (sflag == 1) {
        const uint4* row = (const uint4*)((const unsigned int*)adj + (size_t)i * NNODES);
#pragma unroll
        for (int w = 0; w < 4; ++w) {
            uint4 v = row[w * 256 + t];
            unsigned wd[4] = {v.x, v.y, v.z, v.w};
#pragma unroll
            for (int j = 0; j < 4; ++j) {
                bool on = wd[j] != 0;
                unsigned long long m = __ballot(on);
                int pre = __popcll(m & ((1ull << lane) - 1ull));
                if (on && cnt + pre < CAP)
                    lists[wv][cnt + pre] = (w * 256 + t) * 4 + j;
                cnt += __popcll(m);
            }
        }
    } else {
        uint4 v = ((const uint4*)(adj + (size_t)i * NNODES))[t];
        unsigned wd[4] = {v.x, v.y, v.z, v.w};
#pragma unroll
        for (int j = 0; j < 4; ++j)
#pragma unroll
            for (int b = 0; b < 4; ++b) {
                bool on = ((wd[j] >> (8 * b)) & 0xffu) != 0;
                unsigned long long m = __ballot(on);
                int pre = __popcll(m & ((1ull << lane) - 1ull));
                if (on && cnt + pre < CAP)
                    lists[wv][cnt + pre] = t * 16 + j * 4 + b;
                cnt += __popcll(m);
            }
    }
    if (lane == 0) cnts[wv] = cnt < CAP ? cnt : CAP;
    __syncthreads();
    int offw = 0;
#pragma unroll
    for (int w2 = 0; w2 < 4; ++w2) if (w2 < wv) offw += cnts[w2];
    int myc = cnts[wv];
    for (int k = lane; k < myc; k += 64) {
        int pos = offw + k;
        if (pos < CAP) nbr[(size_t)i * CAP + pos] = lists[wv][k];
    }
    if (t == 0) {
        int tot = cnts[0] + cnts[1] + cnts[2] + cnts[3];
        deg[i] = tot < CAP ? tot : CAP;
    }
}

// ---------------- attention + residual + LayerNorm -------------------------
__global__ __launch_bounds__(256) void attn_ln_kernel(
    const float* __restrict__ xh, const float* __restrict__ x0,
    const float* __restrict__ asrc, const float* __restrict__ atgt,
    const int* __restrict__ nbr, const int* __restrict__ deg_,
    const float* __restrict__ ln_g, const float* __restrict__ ln_b,
    float* __restrict__ xln, u16* __restrict__ xln16)
{
    __shared__ float att[CAP * 4];
    __shared__ int nb[CAP];
    __shared__ float red[8];
    const int i = blockIdx.x;
    const int t = threadIdx.x;
    const int dg = deg_[i];

    for (int k = t; k < dg; k += 256) nb[k] = nbr[(size_t)i * CAP + k];
    __syncthreads();

    for (int idx = t; idx < dg * 4; idx += 256) {
        int k = idx >> 2, h = idx & 3;
        float e = asrc[nb[k] * 4 + h] + atgt[i * 4 + h];
        att[idx] = e > 0.f ? e : 0.2f * e;
    }
    __syncthreads();

    const int wv = t >> 6, lane = t & 63;
    {
        const int h = wv;
        float m = -1e30f;
        for (int k = lane; k < dg; k += 64) m = fmaxf(m, att[k * 4 + h]);
#pragma unroll
        for (int off = 32; off > 0; off >>= 1) m = fmaxf(m, __shfl_xor(m, off));
        float s = 0.f;
        for (int k = lane; k < dg; k += 64) s += expf(att[k * 4 + h] - m);
#pragma unroll
        for (int off = 32; off > 0; off >>= 1) s += __shfl_xor(s, off);
        float inv = 1.0f / s;
        for (int k = lane; k < dg; k += 64)
            att[k * 4 + h] = expf(att[k * 4 + h] - m) * inv;
    }
    __syncthreads();

    const int h = t >> 6;
    float acc = 0.f;
    int k = 0;
    for (; k + 4 <= dg; k += 4) {
        float a0 = att[(k + 0) * 4 + h], v0 = xh[(size_t)nb[k + 0] * 256 + t];
        float a1 = att[(k + 1) * 4 + h], v1 = xh[(size_t)nb[k + 1] * 256 + t];
        float a2 = att[(k + 2) * 4 + h], v2 = xh[(size_t)nb[k + 2] * 256 + t];
        float a3 = att[(k + 3) * 4 + h], v3 = xh[(size_t)nb[k + 3] * 256 + t];
        acc = fmaf(a0, v0, acc); acc = fmaf(a1, v1, acc);
        acc = fmaf(a2, v2, acc); acc = fmaf(a3, v3, acc);
    }
    for (; k < dg; ++k)
        acc = fmaf(att[k * 4 + h], xh[(size_t)nb[k] * 256 + t], acc);

    float v = x0[(size_t)i * 256 + t] + acc;
    float s = v, q = v * v;
#pragma unroll
    for (int off = 32; off > 0; off >>= 1) {
        s += __shfl_xor(s, off);
        q += __shfl_xor(q, off);
    }
    if (lane == 0) { red[wv] = s; red[4 + wv] = q; }
    __syncthreads();
    float S = red[0] + red[1] + red[2] + red[3];
    float Q = red[4] + red[5] + red[6] + red[7];
    float mu = S * (1.0f / 256.0f);
    float var = Q * (1.0f / 256.0f) - mu * mu;
    float y = (v - mu) * rsqrtf(var + 1e-5f) * ln_g[t] + ln_b[t];
    xln[(size_t)i * 256 + t] = y;
    xln16[(size_t)i * 256 + t] = f2bf(y);
}

// ---------------------------------------------------------------------------
extern "C" void kernel_launch(void* const* d_in, const int* in_sizes, int n_in,
                              void* d_out, int out_size, void* d_ws, size_t ws_size,
                              hipStream_t stream)
{
    const float* nf      = (const float*)d_in[0];
    const float* pre_g1  = (const float*)d_in[1];
    const float* pre_b1  = (const float*)d_in[2];
    const float* pre_W1  = (const float*)d_in[3];
    const float* pre_c1  = (const float*)d_in[4];
    const float* pre_g2  = (const float*)d_in[5];
    const float* pre_b2  = (const float*)d_in[6];
    const float* pre_W2  = (const float*)d_in[7];
    const float* pre_c2  = (const float*)d_in[8];
    const float* Wp      = (const float*)d_in[9];
    const float* Wa      = (const float*)d_in[10];
    const float* ln_g    = (const float*)d_in[11];
    const float* ln_b    = (const float*)d_in[12];
    const float* post_g1 = (const float*)d_in[13];
    const float* post_b1 = (const float*)d_in[14];
    const float* post_W1 = (const float*)d_in[15];
    const float* post_c1 = (const float*)d_in[16];
    const float* post_g2 = (const float*)d_in[17];
    const float* post_b2 = (const float*)d_in[18];
    const float* post_W2 = (const float*)d_in[19];
    const float* post_c2 = (const float*)d_in[20];
    const float* Wl      = (const float*)d_in[21];
    const float* cl      = (const float*)d_in[22];
    const unsigned char* adj = (const unsigned char*)d_in[23];
    const int* idxs      = (const int*)d_in[24];
    float* out = (float*)d_out;

    size_t off = 0;
    char* base = (char*)d_ws;
    auto carve = [&](size_t bytes) {
        void* p = base + off;
        off += (bytes + 255) & ~(size_t)255;
        return p;
    };
    u16*   Y16   = (u16*)  carve((size_t)4096 * 1024 * 2);
    u16*   NF16  = (u16*)  carve((size_t)4096 * 512 * 2);
    float* X032  = (float*)carve((size_t)4096 * 256 * 4);
    u16*   X016  = (u16*)  carve((size_t)4096 * 256 * 2);
    float* XH32  = (float*)carve((size_t)4096 * 256 * 4);
    float* XLN32 = (float*)carve((size_t)4096 * 256 * 4);
    u16*   XLN16 = (u16*)  carve((size_t)4096 * 256 * 2);
    u16*   XF16  = (u16*)  carve((size_t)4096 * 256 * 2);
    u16*   W1_16 = (u16*)  carve((size_t)1024 * 512 * 2);
    u16*   W2_16 = (u16*)  carve((size_t)256 * 1024 * 2);
    u16*   Wp16  = (u16*)  carve((size_t)256 * 256 * 2);
    u16*   W3_16 = (u16*)  carve((size_t)1024 * 256 * 2);
    u16*   W4_16 = (u16*)  carve((size_t)256 * 1024 * 2);
    u16*   WlP16 = (u16*)  carve((size_t)64 * 256 * 2);
    float* B1    = (float*)carve(1024 * 4);
    float* B2    = (float*)carve(256 * 4);
    float* BP    = (float*)carve(256 * 4);
    float* B3    = (float*)carve(1024 * 4);
    float* B4    = (float*)carve(256 * 4);
    float* CLP   = (float*)carve(64 * 4);
    int*   NBR   = (int*)  carve((size_t)4096 * CAP * 4);
    int*   DEG   = (int*)  carve((size_t)4096 * 4);
    float* ASRC  = (float*)carve((size_t)4096 * 4 * 4);
    float* ATGT  = (float*)carve((size_t)4096 * 4 * 4);
    float* PART  = (float*)carve((size_t)256 * 1024 * 2 * 4);  // 2 MB
    float* SCL1  = (float*)carve(512 * 4);
    float* SHF1  = (float*)carve(512 * 4);
    float* SCL2  = (float*)carve(1024 * 4);
    float* SHF2  = (float*)carve(1024 * 4);
    float* SCL3  = (float*)carve(256 * 4);
    float* SHF3  = (float*)carve(256 * 4);
    float* SCL4  = (float*)carve(1024 * 4);
    float* SHF4  = (float*)carve(1024 * 4);
    (void)ws_size; (void)n_in; (void)in_sizes; (void)out_size;

    const int NB = 128, RPB = 4096 / 128;

    // neighbor lists early (independent of FFN chain); probe inlined
    build_nbr_kernel<<<4096, 256, 0, stream>>>(adj, NBR, DEG);

    // --- stage 1: BN1 fold + GEMM1 (Y = gelu(bn(nf)@W1^T+c1)) -> Y16
    colstats_partial<2, true><<<NB, 256, 0, stream>>>(nf, PART, NF16, RPB);
    colstats_final<<<2, 256, 0, stream>>>(PART, pre_g1, pre_b1, SCL1, SHF1, NB, 512);
    foldw_kernel<<<1024, 256, 0, stream>>>(pre_W1, SCL1, SHF1, pre_c1, W1_16, B1, 512, 1024);
    mfma_gemm<true, false, true><<<dim3(16, 64), 256, 0, stream>>>(
        NF16, W1_16, B1, nullptr, Y16, 4096, 1024, 512);

    // --- stage 2: BN2 fold + GEMM2 (X0) -> X032 + X016
    colstats_partial_b16<4><<<NB, 256, 0, stream>>>(Y16, PART, RPB);
    colstats_final<<<4, 256, 0, stream>>>(PART, pre_g2, pre_b2, SCL2, SHF2, 256, 1024);
    foldw_kernel<<<256, 256, 0, stream>>>(pre_W2, SCL2, SHF2, pre_c2, W2_16, B2, 1024, 256);
    mfma_gemm<true, true, true><<<dim3(4, 64), 256, 0, stream>>>(
        Y16, W2_16, B2, X032, X016, 4096, 256, 1024);

    // --- stage 3: GEMM3 (XH = X0 @ Wp^T) -> XH32
    foldw_kernel<<<256, 256, 0, stream>>>(Wp, nullptr, nullptr, nullptr, Wp16, BP, 256, 256);
    mfma_gemm<false, true, false><<<dim3(4, 64), 256, 0, stream>>>(
        X016, Wp16, nullptr, XH32, nullptr, 4096, 256, 256);

    // --- attention
    asrc_atgt_kernel<<<1024, 256, 0, stream>>>(XH32, Wa, ASRC, ATGT);
    attn_ln_kernel<<<4096, 256, 0, stream>>>(XH32, X032, ASRC, ATGT, NBR, DEG,
                                             ln_g, ln_b, XLN32, XLN16);

    // --- stage 4: BN3 fold + GEMM4 -> Y16
    colstats_partial<1, false><<<NB, 256, 0, stream>>>(XLN32, PART, nullptr, RPB);
    colstats_final<<<1, 256, 0, stream>>>(PART, post_g1, post_b1, SCL3, SHF3, NB, 256);
    foldw_kernel<<<1024, 256, 0, stream>>>(post_W1, SCL3, SHF3, post_c1, W3_16, B3, 256, 1024);
    mfma_gemm<true, false, true><<<dim3(16, 64), 256, 0, stream>>>(
        XLN16, W3_16, B3, nullptr, Y16, 4096, 1024, 256);

    // --- stage 5: BN4 fold + GEMM5 -> XF16 (bf16 only; logits consumes bf16)
    colstats_partial_b16<4><<<NB, 256, 0, stream>>>(Y16, PART, RPB);
    colstats_final<<<4, 256, 0, stream>>>(PART, post_g2, post_b2, SCL4, SHF4, 256, 1024);
    foldw_kernel<<<256, 256, 0, stream>>>(post_W2, SCL4, SHF4, post_c2, W4_16, B4, 1024, 256);
    mfma_gemm<true, false, true><<<dim3(4, 64), 256, 0, stream>>>(
        Y16, W4_16, B4, nullptr, XF16, 4096, 256, 1024);

    // --- logits: fold Wl (pad 40->64) + gathered MFMA GEMM
    foldw_kernel<<<64, 256, 0, stream>>>(Wl, nullptr, nullptr, cl, WlP16, CLP, 256, 40);
    logits_mfma<<<128, 256, 0, stream>>>(XF16, idxs, WlP16, CLP, out);
}

// Round 7
// 171.461 us; speedup vs baseline: 2.1655x; 2.1655x over previous
//
#include <hip/hip_runtime.h>
#include <hip/hip_bf16.h>

// ---------------------------------------------------------------------------
// GANClassifier forward, round 6: parallel colstats_final (the R5 profile
// showed the 5 final-reduction dispatches were ~266 of 371 us: 4-16 blocks
// with a serialized 256-iteration load loop = pure latency bound).
// Now: block = 16 cols x 16 slice-groups, grid = C/16, LDS combine.
// ---------------------------------------------------------------------------

#define NNODES 4096
#define CAP 128

typedef unsigned short u16;
typedef __attribute__((ext_vector_type(8))) short bf16x8;
typedef __attribute__((ext_vector_type(4))) float f32x4;

__device__ __forceinline__ float gelu_f(float x) {
    return 0.5f * x * (1.0f + erff(x * 0.70710678118654752f));
}
__device__ __forceinline__ u16 f2bf(float x) {
    union { float f; unsigned u; } v; v.f = x;
    unsigned r = v.u + 0x7fff + ((v.u >> 16) & 1);
    return (u16)(r >> 16);
}
__device__ __forceinline__ float bf2f(u16 b) {
    return __uint_as_float(((unsigned)b) << 16);
}
__device__ __forceinline__ void gload16(const void* g, void* l) {
    __builtin_amdgcn_global_load_lds(
        (const __attribute__((address_space(1))) unsigned int*)g,
        (__attribute__((address_space(3))) unsigned int*)l, 16, 0, 0);
}

// ---------------- column stats (fp32 input, optional bf16 copy-out) --------
template<int CPT, bool CVT>
__global__ __launch_bounds__(256) void colstats_partial(
    const float* __restrict__ X, float* __restrict__ part,
    u16* __restrict__ x16, int rpb)
{
    const int C = CPT * 256;
    const int r0 = blockIdx.x * rpb;
    const int t = threadIdx.x;
    float s[CPT], q[CPT];
#pragma unroll
    for (int cc = 0; cc < CPT; ++cc) { s[cc] = 0.f; q[cc] = 0.f; }
    for (int r = 0; r < rpb; ++r) {
        const float* row = X + (size_t)(r0 + r) * C;
#pragma unroll
        for (int cc = 0; cc < CPT; ++cc) {
            float v = row[cc * 256 + t];
            s[cc] += v; q[cc] += v * v;
            if (CVT) x16[(size_t)(r0 + r) * C + cc * 256 + t] = f2bf(v);
        }
    }
#pragma unroll
    for (int cc = 0; cc < CPT; ++cc) {
        int c = cc * 256 + t;
        part[((size_t)blockIdx.x * C + c) * 2 + 0] = s[cc];
        part[((size_t)blockIdx.x * C + c) * 2 + 1] = q[cc];
    }
}

// ---------------- column stats (bf16 input, uint4-vectorized) --------------
template<int CPT>
__global__ __launch_bounds__(256) void colstats_partial_b16(
    const u16* __restrict__ X, float* __restrict__ part, int rpb)
{
    const int C = CPT * 256;
    const int CW = C / 8;            // uint4 chunks per row
    const int rstep = 256 / CW;      // row sub-passes per iteration
    const int t = threadIdx.x;
    const int cchunk = t % CW;
    const int rsub = t / CW;
    const int r0 = blockIdx.x * rpb;
    float s[8], q[8];
#pragma unroll
    for (int j = 0; j < 8; ++j) { s[j] = 0.f; q[j] = 0.f; }
    for (int r = rsub; r < rpb; r += rstep) {
        uint4 v = *(const uint4*)(X + (size_t)(r0 + r) * C + cchunk * 8);
        unsigned wd[4] = {v.x, v.y, v.z, v.w};
#pragma unroll
        for (int j = 0; j < 4; ++j) {
            float lo = bf2f((u16)(wd[j] & 0xffffu));
            float hi = bf2f((u16)(wd[j] >> 16));
            s[2 * j] += lo;     q[2 * j] += lo * lo;
            s[2 * j + 1] += hi; q[2 * j + 1] += hi * hi;
        }
    }
#pragma unroll
    for (int j = 0; j < 8; ++j) {
        int c = cchunk * 8 + j;
        size_t slice = (size_t)blockIdx.x * rstep + rsub;
        part[(slice * C + c) * 2 + 0] = s[j];
        part[(slice * C + c) * 2 + 1] = q[j];
    }
}

// ---------------- final reduction: 16 cols x 16 slice-groups per block -----
__global__ __launch_bounds__(256) void colstats_final(
    const float* __restrict__ part, const float* __restrict__ g,
    const float* __restrict__ bt, float* __restrict__ scl,
    float* __restrict__ shf, int NB, int C)
{
    __shared__ float sred[16][17];
    __shared__ float qred[16][17];
    const int t = threadIdx.x;
    const int cs = t & 15, grp = t >> 4;
    const int c = blockIdx.x * 16 + cs;
    float s = 0.f, q = 0.f;
    for (int b = grp; b < NB; b += 16) {
        s += part[((size_t)b * C + c) * 2 + 0];
        q += part[((size_t)b * C + c) * 2 + 1];
    }
    sred[grp][cs] = s; qred[grp][cs] = q;
    __syncthreads();
    if (grp == 0) {
        float S = 0.f, Q = 0.f;
#pragma unroll
        for (int j = 0; j < 16; ++j) { S += sred[j][cs]; Q += qred[j][cs]; }
        float m = S * (1.0f / 4096.0f);
        float v = Q * (1.0f / 4096.0f) - m * m;
        float sc = g[c] * rsqrtf(v + 1e-5f);
        scl[c] = sc;
        shf[c] = bt[c] - m * sc;
    }
}

// ---------------- fold BN into weights: W16 = bf16(W*scl), b' = c + W@shf --
__global__ __launch_bounds__(256) void foldw_kernel(
    const float* __restrict__ W, const float* __restrict__ scl,
    const float* __restrict__ shf, const float* __restrict__ bias,
    u16* __restrict__ W16, float* __restrict__ bout, int K, int nvalid)
{
    __shared__ float red[4];
    const int n = blockIdx.x, t = threadIdx.x;
    u16* o = W16 + (size_t)n * K;
    if (n >= nvalid) {
        for (int k = t; k < K; k += 256) o[k] = 0;
        if (t == 0) bout[n] = 0.f;
        return;
    }
    const float* w = W + (size_t)n * K;
    float part = 0.f;
    for (int k = t; k < K; k += 256) {
        float wv = w[k];
        float s = scl ? scl[k] : 1.f;
        float f = shf ? shf[k] : 0.f;
        o[k] = f2bf(wv * s);
        part += wv * f;
    }
    int lane = t & 63, wv_ = t >> 6;
#pragma unroll
    for (int off = 32; off > 0; off >>= 1) part += __shfl_down(part, off);
    if (lane == 0) red[wv_] = part;
    __syncthreads();
    if (t == 0)
        bout[n] = (bias ? bias[n] : 0.f) + red[0] + red[1] + red[2] + red[3];
}

// ---------------- bf16 MFMA GEMM: C = epi(A @ W^T + bias) ------------------
template<bool EPI, bool S32, bool S16>
__global__ __launch_bounds__(256) void mfma_gemm(
    const u16* __restrict__ A, const u16* __restrict__ W,
    const float* __restrict__ bias, float* __restrict__ C32,
    u16* __restrict__ C16, int M, int N, int K)
{
    __shared__ u16 As[64 * 64];
    __shared__ u16 Bs[64 * 64];
    const int t = threadIdx.x;
    const int lane = t & 63, wv = t >> 6;
    const int wm = (wv >> 1) * 32, wn = (wv & 1) * 32;
    const int tile_m = blockIdx.y * 64, tile_n = blockIdx.x * 64;

    f32x4 acc[2][2];
#pragma unroll
    for (int i = 0; i < 2; ++i)
#pragma unroll
        for (int j = 0; j < 2; ++j)
#pragma unroll
            for (int e = 0; e < 4; ++e) acc[i][j][e] = 0.f;

    int srow[2], soff[2];
#pragma unroll
    for (int i = 0; i < 2; ++i) {
        int f = i * 256 + t;
        srow[i] = f >> 3;
        soff[i] = ((f & 7) ^ (srow[i] & 7)) * 8;
    }
    char* ldsA0 = (char*)As + (t >> 6) * 1024;
    char* ldsB0 = (char*)Bs + (t >> 6) * 1024;
    const int frow_a0 = wm + (lane & 15);
    const int frow_b0 = wn + (lane & 15);
    const int fk = (lane >> 4) * 16;

    const int NT = K >> 6;
    for (int kt = 0; kt < NT; ++kt) {
#pragma unroll
        for (int i = 0; i < 2; ++i) {
            gload16(A + (size_t)(tile_m + srow[i]) * K + kt * 64 + soff[i],
                    ldsA0 + i * 4096);
            gload16(W + (size_t)(tile_n + srow[i]) * K + kt * 64 + soff[i],
                    ldsB0 + i * 4096);
        }
        __syncthreads();
#pragma unroll
        for (int kk = 0; kk < 2; ++kk) {
            bf16x8 a[2], b[2];
#pragma unroll
            for (int mi = 0; mi < 2; ++mi) {
                int r = frow_a0 + mi * 16;
                a[mi] = *(const bf16x8*)((const char*)As + r * 128 +
                        ((kk * 64 + fk) ^ ((r & 7) << 4)));
            }
#pragma unroll
            for (int ni = 0; ni < 2; ++ni) {
                int r = frow_b0 + ni * 16;
                b[ni] = *(const bf16x8*)((const char*)Bs + r * 128 +
                        ((kk * 64 + fk) ^ ((r & 7) << 4)));
            }
#pragma unroll
            for (int mi = 0; mi < 2; ++mi)
#pragma unroll
                for (int ni = 0; ni < 2; ++ni)
                    acc[mi][ni] = __builtin_amdgcn_mfma_f32_16x16x32_bf16(
                        a[mi], b[ni], acc[mi][ni], 0, 0, 0);
        }
        __syncthreads();
    }

#pragma unroll
    for (int mi = 0; mi < 2; ++mi) {
#pragma unroll
        for (int ni = 0; ni < 2; ++ni) {
            int col = tile_n + wn + ni * 16 + (lane & 15);
            float bs = 0.f;
            if (EPI) bs = bias[col];
#pragma unroll
            for (int e = 0; e < 4; ++e) {
                int row = tile_m + wm + mi * 16 + ((lane >> 4) << 2) + e;
                float c = acc[mi][ni][e];
                if (EPI) c = gelu_f(c + bs);
                if (S32) C32[(size_t)row * N + col] = c;
                if (S16) C16[(size_t)row * N + col] = f2bf(c);
            }
        }
    }
}

// ---------------- gathered logits GEMM: out = XF16[idx] @ WlP^T + cl -------
__global__ __launch_bounds__(256) void logits_mfma(
    const u16* __restrict__ xf16, const int* __restrict__ idxs,
    const u16* __restrict__ WlP, const float* __restrict__ clP,
    float* __restrict__ out)
{
    __shared__ u16 As[64 * 64];
    __shared__ u16 Bs[64 * 64];
    const int t = threadIdx.x;
    const int lane = t & 63, wv = t >> 6;
    const int wm = (wv >> 1) * 32, wn = (wv & 1) * 32;
    const int tile_m = blockIdx.x * 64;

    f32x4 acc[2][2];
#pragma unroll
    for (int i = 0; i < 2; ++i)
#pragma unroll
        for (int j = 0; j < 2; ++j)
#pragma unroll
            for (int e = 0; e < 4; ++e) acc[i][j][e] = 0.f;

    int srow[2], soff[2], gr[2];
#pragma unroll
    for (int i = 0; i < 2; ++i) {
        int f = i * 256 + t;
        srow[i] = f >> 3;
        soff[i] = ((f & 7) ^ (srow[i] & 7)) * 8;
        gr[i] = idxs[tile_m + srow[i]];
    }
    char* ldsA0 = (char*)As + (t >> 6) * 1024;
    char* ldsB0 = (char*)Bs + (t >> 6) * 1024;
    const int frow_a0 = wm + (lane & 15);
    const int frow_b0 = wn + (lane & 15);
    const int fk = (lane >> 4) * 16;

#pragma unroll
    for (int kt = 0; kt < 4; ++kt) {             // K = 256
#pragma unroll
        for (int i = 0; i < 2; ++i) {
            gload16(xf16 + (size_t)gr[i] * 256 + kt * 64 + soff[i],
                    ldsA0 + i * 4096);
            gload16(WlP + (size_t)srow[i] * 256 + kt * 64 + soff[i],
                    ldsB0 + i * 4096);
        }
        __syncthreads();
#pragma unroll
        for (int kk = 0; kk < 2; ++kk) {
            bf16x8 a[2], b[2];
#pragma unroll
            for (int mi = 0; mi < 2; ++mi) {
                int r = frow_a0 + mi * 16;
                a[mi] = *(const bf16x8*)((const char*)As + r * 128 +
                        ((kk * 64 + fk) ^ ((r & 7) << 4)));
            }
#pragma unroll
            for (int ni = 0; ni < 2; ++ni) {
                int r = frow_b0 + ni * 16;
                b[ni] = *(const bf16x8*)((const char*)Bs + r * 128 +
                        ((kk * 64 + fk) ^ ((r & 7) << 4)));
            }
#pragma unroll
            for (int mi = 0; mi < 2; ++mi)
#pragma unroll
                for (int ni = 0; ni < 2; ++ni)
                    acc[mi][ni] = __builtin_amdgcn_mfma_f32_16x16x32_bf16(
                        a[mi], b[ni], acc[mi][ni], 0, 0, 0);
        }
        __syncthreads();
    }

#pragma unroll
    for (int mi = 0; mi < 2; ++mi) {
#pragma unroll
        for (int ni = 0; ni < 2; ++ni) {
            int col = wn + ni * 16 + (lane & 15);
            if (col < 40) {
                float bs = clP[col];
#pragma unroll
                for (int e = 0; e < 4; ++e) {
                    int row = tile_m + wm + mi * 16 + ((lane >> 4) << 2) + e;
                    out[(size_t)row * 40 + col] = acc[mi][ni][e] + bs;
                }
            }
        }
    }
}

// ---------------- a_src / a_tgt --------------------------------------------
__global__ __launch_bounds__(256) void asrc_atgt_kernel(
    const float* __restrict__ xh, const float* __restrict__ Wa,
    float* __restrict__ asrc, float* __restrict__ atgt)
{
    int node = (blockIdx.x * 256 + threadIdx.x) >> 6;
    int lane = threadIdx.x & 63;
    const float* row = xh + (size_t)node * 256;
    float ws = Wa[lane], wt = Wa[64 + lane];
    float s[4], tt[4];
#pragma unroll
    for (int h = 0; h < 4; ++h) {
        float v = row[h * 64 + lane];
        s[h] = v * ws; tt[h] = v * wt;
    }
#pragma unroll
    for (int off = 32; off > 0; off >>= 1) {
#pragma unroll
        for (int h = 0; h < 4; ++h) {
            s[h] += __shfl_down(s[h], off);
            tt[h] += __shfl_down(tt[h], off);
        }
    }
    if (lane == 0) {
#pragma unroll
        for (int h = 0; h < 4; ++h) {
            asrc[node * 4 + h] = s[h];
            atgt[node * 4 + h] = tt[h];
        }
    }
}

// ---------------- adjacency -> neighbor lists (block per row) --------------
__global__ __launch_bounds__(256) void build_nbr_kernel(
    const unsigned char* __restrict__ adj, int* __restrict__ nbr,
    int* __restrict__ deg)
{
    __shared__ int lists[4][CAP];
    __shared__ int cnts[4];
    __shared__ int sflag;
    const int i = blockIdx.x;
    const int t = threadIdx.x;
    const int wv = t >> 6, lane = t & 63;

    if (wv == 0) {
        bool a = adj[(size_t)lane * 4097] != 0;
        bool b = ((const unsigned int*)adj)[(size_t)lane * 4097] != 0;
        unsigned long long mA = __ballot(a);
        unsigned long long mB = __ballot(b);
        if (lane == 0) sflag = (__popcll(mA) >= __popcll(mB)) ? 0 : 1;
    }
    __syncthreads();
    int cnt = 0;

    if (sflag == 1) {
        const uint4* row = (const uint4*)((const unsigned int*)adj + (size_t)i * NNODES);
#pragma unroll
        for (int w = 0; w < 4; ++w) {
            uint4 v = row[w * 256 + t];
            unsigned wd[4] = {v.x, v.y, v.z, v.w};
#pragma unroll
            for (int j = 0; j < 4; ++j) {
                bool on = wd[j] != 0;
                unsigned long long m = __ballot(on);
                int pre = __popcll(m & ((1ull << lane) - 1ull));
                if (on && cnt + pre < CAP)
                    lists[wv][cnt + pre] = (w * 256 + t) * 4 + j;
                cnt += __popcll(m);
            }
        }
    } else {
        uint4 v = ((const uint4*)(adj + (size_t)i * NNODES))[t];
        unsigned wd[4] = {v.x, v.y, v.z, v.w};
#pragma unroll
        for (int j = 0; j < 4; ++j)
#pragma unroll
            for (int b = 0; b < 4; ++b) {
                bool on = ((wd[j] >> (8 * b)) & 0xffu) != 0;
                unsigned long long m = __ballot(on);
                int pre = __popcll(m & ((1ull << lane) - 1ull));
                if (on && cnt + pre < CAP)
                    lists[wv][cnt + pre] = t * 16 + j * 4 + b;
                cnt += __popcll(m);
            }
    }
    if (lane == 0) cnts[wv] = cnt < CAP ? cnt : CAP;
    __syncthreads();
    int offw = 0;
#pragma unroll
    for (int w2 = 0; w2 < 4; ++w2) if (w2 < wv) offw += cnts[w2];
    int myc = cnts[wv];
    for (int k = lane; k < myc; k += 64) {
        int pos = offw + k;
        if (pos < CAP) nbr[(size_t)i * CAP + pos] = lists[wv][k];
    }
    if (t == 0) {
        int tot = cnts[0] + cnts[1] + cnts[2] + cnts[3];
        deg[i] = tot < CAP ? tot : CAP;
    }
}

// ---------------- attention + residual + LayerNorm -------------------------
__global__ __launch_bounds__(256) void attn_ln_kernel(
    const float* __restrict__ xh, const float* __restrict__ x0,
    const float* __restrict__ asrc, const float* __restrict__ atgt,
    const int* __restrict__ nbr, const int* __restrict__ deg_,
    const float* __restrict__ ln_g, const float* __restrict__ ln_b,
    float* __restrict__ xln, u16* __restrict__ xln16)
{
    __shared__ float att[CAP * 4];
    __shared__ int nb[CAP];
    __shared__ float red[8];
    const int i = blockIdx.x;
    const int t = threadIdx.x;
    const int dg = deg_[i];

    for (int k = t; k < dg; k += 256) nb[k] = nbr[(size_t)i * CAP + k];
    __syncthreads();

    for (int idx = t; idx < dg * 4; idx += 256) {
        int k = idx >> 2, h = idx & 3;
        float e = asrc[nb[k] * 4 + h] + atgt[i * 4 + h];
        att[idx] = e > 0.f ? e : 0.2f * e;
    }
    __syncthreads();

    const int wv = t >> 6, lane = t & 63;
    {
        const int h = wv;
        float m = -1e30f;
        for (int k = lane; k < dg; k += 64) m = fmaxf(m, att[k * 4 + h]);
#pragma unroll
        for (int off = 32; off > 0; off >>= 1) m = fmaxf(m, __shfl_xor(m, off));
        float s = 0.f;
        for (int k = lane; k < dg; k += 64) s += expf(att[k * 4 + h] - m);
#pragma unroll
        for (int off = 32; off > 0; off >>= 1) s += __shfl_xor(s, off);
        float inv = 1.0f / s;
        for (int k = lane; k < dg; k += 64)
            att[k * 4 + h] = expf(att[k * 4 + h] - m) * inv;
    }
    __syncthreads();

    const int h = t >> 6;
    float acc = 0.f;
    int k = 0;
    for (; k + 4 <= dg; k += 4) {
        float a0 = att[(k + 0) * 4 + h], v0 = xh[(size_t)nb[k + 0] * 256 + t];
        float a1 = att[(k + 1) * 4 + h], v1 = xh[(size_t)nb[k + 1] * 256 + t];
        float a2 = att[(k + 2) * 4 + h], v2 = xh[(size_t)nb[k + 2] * 256 + t];
        float a3 = att[(k + 3) * 4 + h], v3 = xh[(size_t)nb[k + 3] * 256 + t];
        acc = fmaf(a0, v0, acc); acc = fmaf(a1, v1, acc);
        acc = fmaf(a2, v2, acc); acc = fmaf(a3, v3, acc);
    }
    for (; k < dg; ++k)
        acc = fmaf(att[k * 4 + h], xh[(size_t)nb[k] * 256 + t], acc);

    float v = x0[(size_t)i * 256 + t] + acc;
    float s = v, q = v * v;
#pragma unroll
    for (int off = 32; off > 0; off >>= 1) {
        s += __shfl_xor(s, off);
        q += __shfl_xor(q, off);
    }
    if (lane == 0) { red[wv] = s; red[4 + wv] = q; }
    __syncthreads();
    float S = red[0] + red[1] + red[2] + red[3];
    float Q = red[4] + red[5] + red[6] + red[7];
    float mu = S * (1.0f / 256.0f);
    float var = Q * (1.0f / 256.0f) - mu * mu;
    float y = (v - mu) * rsqrtf(var + 1e-5f) * ln_g[t] + ln_b[t];
    xln[(size_t)i * 256 + t] = y;
    xln16[(size_t)i * 256 + t] = f2bf(y);
}

// ---------------------------------------------------------------------------
extern "C" void kernel_launch(void* const* d_in, const int* in_sizes, int n_in,
                              void* d_out, int out_size, void* d_ws, size_t ws_size,
                              hipStream_t stream)
{
    const float* nf      = (const float*)d_in[0];
    const float* pre_g1  = (const float*)d_in[1];
    const float* pre_b1  = (const float*)d_in[2];
    const float* pre_W1  = (const float*)d_in[3];
    const float* pre_c1  = (const float*)d_in[4];
    const float* pre_g2  = (const float*)d_in[5];
    const float* pre_b2  = (const float*)d_in[6];
    const float* pre_W2  = (const float*)d_in[7];
    const float* pre_c2  = (const float*)d_in[8];
    const float* Wp      = (const float*)d_in[9];
    const float* Wa      = (const float*)d_in[10];
    const float* ln_g    = (const float*)d_in[11];
    const float* ln_b    = (const float*)d_in[12];
    const float* post_g1 = (const float*)d_in[13];
    const float* post_b1 = (const float*)d_in[14];
    const float* post_W1 = (const float*)d_in[15];
    const float* post_c1 = (const float*)d_in[16];
    const float* post_g2 = (const float*)d_in[17];
    const float* post_b2 = (const float*)d_in[18];
    const float* post_W2 = (const float*)d_in[19];
    const float* post_c2 = (const float*)d_in[20];
    const float* Wl      = (const float*)d_in[21];
    const float* cl      = (const float*)d_in[22];
    const unsigned char* adj = (const unsigned char*)d_in[23];
    const int* idxs      = (const int*)d_in[24];
    float* out = (float*)d_out;

    size_t off = 0;
    char* base = (char*)d_ws;
    auto carve = [&](size_t bytes) {
        void* p = base + off;
        off += (bytes + 255) & ~(size_t)255;
        return p;
    };
    u16*   Y16   = (u16*)  carve((size_t)4096 * 1024 * 2);
    u16*   NF16  = (u16*)  carve((size_t)4096 * 512 * 2);
    float* X032  = (float*)carve((size_t)4096 * 256 * 4);
    u16*   X016  = (u16*)  carve((size_t)4096 * 256 * 2);
    float* XH32  = (float*)carve((size_t)4096 * 256 * 4);
    float* XLN32 = (float*)carve((size_t)4096 * 256 * 4);
    u16*   XLN16 = (u16*)  carve((size_t)4096 * 256 * 2);
    u16*   XF16  = (u16*)  carve((size_t)4096 * 256 * 2);
    u16*   W1_16 = (u16*)  carve((size_t)1024 * 512 * 2);
    u16*   W2_16 = (u16*)  carve((size_t)256 * 1024 * 2);
    u16*   Wp16  = (u16*)  carve((size_t)256 * 256 * 2);
    u16*   W3_16 = (u16*)  carve((size_t)1024 * 256 * 2);
    u16*   W4_16 = (u16*)  carve((size_t)256 * 1024 * 2);
    u16*   WlP16 = (u16*)  carve((size_t)64 * 256 * 2);
    float* B1    = (float*)carve(1024 * 4);
    float* B2    = (float*)carve(256 * 4);
    float* BP    = (float*)carve(256 * 4);
    float* B3    = (float*)carve(1024 * 4);
    float* B4    = (float*)carve(256 * 4);
    float* CLP   = (float*)carve(64 * 4);
    int*   NBR   = (int*)  carve((size_t)4096 * CAP * 4);
    int*   DEG   = (int*)  carve((size_t)4096 * 4);
    float* ASRC  = (float*)carve((size_t)4096 * 4 * 4);
    float* ATGT  = (float*)carve((size_t)4096 * 4 * 4);
    float* PART  = (float*)carve((size_t)256 * 1024 * 2 * 4);  // 2 MB
    float* SCL1  = (float*)carve(512 * 4);
    float* SHF1  = (float*)carve(512 * 4);
    float* SCL2  = (float*)carve(1024 * 4);
    float* SHF2  = (float*)carve(1024 * 4);
    float* SCL3  = (float*)carve(256 * 4);
    float* SHF3  = (float*)carve(256 * 4);
    float* SCL4  = (float*)carve(1024 * 4);
    float* SHF4  = (float*)carve(1024 * 4);
    (void)ws_size; (void)n_in; (void)in_sizes; (void)out_size;

    const int NB = 128, RPB = 4096 / 128;

    // neighbor lists early (independent of FFN chain); probe inlined
    build_nbr_kernel<<<4096, 256, 0, stream>>>(adj, NBR, DEG);

    // --- stage 1: BN1 fold + GEMM1 (Y = gelu(bn(nf)@W1^T+c1)) -> Y16
    colstats_partial<2, true><<<NB, 256, 0, stream>>>(nf, PART, NF16, RPB);
    colstats_final<<<512 / 16, 256, 0, stream>>>(PART, pre_g1, pre_b1, SCL1, SHF1, NB, 512);
    foldw_kernel<<<1024, 256, 0, stream>>>(pre_W1, SCL1, SHF1, pre_c1, W1_16, B1, 512, 1024);
    mfma_gemm<true, false, true><<<dim3(16, 64), 256, 0, stream>>>(
        NF16, W1_16, B1, nullptr, Y16, 4096, 1024, 512);

    // --- stage 2: BN2 fold + GEMM2 (X0) -> X032 + X016
    colstats_partial_b16<4><<<NB, 256, 0, stream>>>(Y16, PART, RPB);
    colstats_final<<<1024 / 16, 256, 0, stream>>>(PART, pre_g2, pre_b2, SCL2, SHF2, 256, 1024);
    foldw_kernel<<<256, 256, 0, stream>>>(pre_W2, SCL2, SHF2, pre_c2, W2_16, B2, 1024, 256);
    mfma_gemm<true, true, true><<<dim3(4, 64), 256, 0, stream>>>(
        Y16, W2_16, B2, X032, X016, 4096, 256, 1024);

    // --- stage 3: GEMM3 (XH = X0 @ Wp^T) -> XH32
    foldw_kernel<<<256, 256, 0, stream>>>(Wp, nullptr, nullptr, nullptr, Wp16, BP, 256, 256);
    mfma_gemm<false, true, false><<<dim3(4, 64), 256, 0, stream>>>(
        X016, Wp16, nullptr, XH32, nullptr, 4096, 256, 256);

    // --- attention
    asrc_atgt_kernel<<<1024, 256, 0, stream>>>(XH32, Wa, ASRC, ATGT);
    attn_ln_kernel<<<4096, 256, 0, stream>>>(XH32, X032, ASRC, ATGT, NBR, DEG,
                                             ln_g, ln_b, XLN32, XLN16);

    // --- stage 4: BN3 fold + GEMM4 -> Y16
    colstats_partial<1, false><<<NB, 256, 0, stream>>>(XLN32, PART, nullptr, RPB);
    colstats_final<<<256 / 16, 256, 0, stream>>>(PART, post_g1, post_b1, SCL3, SHF3, NB, 256);
    foldw_kernel<<<1024, 256, 0, stream>>>(post_W1, SCL3, SHF3, post_c1, W3_16, B3, 256, 1024);
    mfma_gemm<true, false, true><<<dim3(16, 64), 256, 0, stream>>>(
        XLN16, W3_16, B3, nullptr, Y16, 4096, 1024, 256);

    // --- stage 5: BN4 fold + GEMM5 -> XF16
    colstats_partial_b16<4><<<NB, 256, 0, stream>>>(Y16, PART, RPB);
    colstats_final<<<1024 / 16, 256, 0, stream>>>(PART, post_g2, post_b2, SCL4, SHF4, 256, 1024);
    foldw_kernel<<<256, 256, 0, stream>>>(post_W2, SCL4, SHF4, post_c2, W4_16, B4, 1024, 256);
    mfma_gemm<true, false, true><<<dim3(4, 64), 256, 0, stream>>>(
        Y16, W4_16, B4, nullptr, XF16, 4096, 256, 1024);

    // --- logits: fold Wl (pad 40->64) + gathered MFMA GEMM
    foldw_kernel<<<64, 256, 0, stream>>>(Wl, nullptr, nullptr, cl, WlP16, CLP, 256, 40);
    logits_mfma<<<128, 256, 0, stream>>>(XF16, idxs, WlP16, CLP, out);
}

// Round 8
// 149.044 us; speedup vs baseline: 2.4912x; 1.1504x over previous
//
#include <hip/hip_runtime.h>
#include <hip/hip_bf16.h>

// ---------------------------------------------------------------------------
// GANClassifier forward, round 7:
//   - All MFMA GEMMs double-buffered (T3-minimum: STAGE(next) issued before
//     compute(cur), one __syncthreads per K-step -> loads overlap MFMA).
//   - BatchNorm colstats fused into GEMM1/GEMM4 epilogues (PART slices by
//     blockIdx.y) -> colstats_partial_b16 passes removed.
//   - a_src/a_tgt fused into GEMM3 epilogue (tile == head); XH bf16-only.
//   - attention gather reads bf16 xh (half traffic).
// ---------------------------------------------------------------------------

#define NNODES 4096
#define CAP 128

typedef unsigned short u16;
typedef __attribute__((ext_vector_type(8))) short bf16x8;
typedef __attribute__((ext_vector_type(4))) float f32x4;

__device__ __forceinline__ float gelu_f(float x) {
    return 0.5f * x * (1.0f + erff(x * 0.70710678118654752f));
}
__device__ __forceinline__ u16 f2bf(float x) {
    union { float f; unsigned u; } v; v.f = x;
    unsigned r = v.u + 0x7fff + ((v.u >> 16) & 1);
    return (u16)(r >> 16);
}
__device__ __forceinline__ float bf2f(u16 b) {
    return __uint_as_float(((unsigned)b) << 16);
}
__device__ __forceinline__ void gload16(const void* g, void* l) {
    __builtin_amdgcn_global_load_lds(
        (const __attribute__((address_space(1))) unsigned int*)g,
        (__attribute__((address_space(3))) unsigned int*)l, 16, 0, 0);
}

// ---------------- column stats (fp32 input, optional bf16 copy-out) --------
template<int CPT, bool CVT>
__global__ __launch_bounds__(256) void colstats_partial(
    const float* __restrict__ X, float* __restrict__ part,
    u16* __restrict__ x16, int rpb)
{
    const int C = CPT * 256;
    const int r0 = blockIdx.x * rpb;
    const int t = threadIdx.x;
    float s[CPT], q[CPT];
#pragma unroll
    for (int cc = 0; cc < CPT; ++cc) { s[cc] = 0.f; q[cc] = 0.f; }
    for (int r = 0; r < rpb; ++r) {
        const float* row = X + (size_t)(r0 + r) * C;
#pragma unroll
        for (int cc = 0; cc < CPT; ++cc) {
            float v = row[cc * 256 + t];
            s[cc] += v; q[cc] += v * v;
            if (CVT) x16[(size_t)(r0 + r) * C + cc * 256 + t] = f2bf(v);
        }
    }
#pragma unroll
    for (int cc = 0; cc < CPT; ++cc) {
        int c = cc * 256 + t;
        part[((size_t)blockIdx.x * C + c) * 2 + 0] = s[cc];
        part[((size_t)blockIdx.x * C + c) * 2 + 1] = q[cc];
    }
}

// ---------------- final reduction: 16 cols x 16 slice-groups per block -----
__global__ __launch_bounds__(256) void colstats_final(
    const float* __restrict__ part, const float* __restrict__ g,
    const float* __restrict__ bt, float* __restrict__ scl,
    float* __restrict__ shf, int NB, int C)
{
    __shared__ float sred[16][17];
    __shared__ float qred[16][17];
    const int t = threadIdx.x;
    const int cs = t & 15, grp = t >> 4;
    const int c = blockIdx.x * 16 + cs;
    float s = 0.f, q = 0.f;
    for (int b = grp; b < NB; b += 16) {
        s += part[((size_t)b * C + c) * 2 + 0];
        q += part[((size_t)b * C + c) * 2 + 1];
    }
    sred[grp][cs] = s; qred[grp][cs] = q;
    __syncthreads();
    if (grp == 0) {
        float S = 0.f, Q = 0.f;
#pragma unroll
        for (int j = 0; j < 16; ++j) { S += sred[j][cs]; Q += qred[j][cs]; }
        float m = S * (1.0f / 4096.0f);
        float v = Q * (1.0f / 4096.0f) - m * m;
        float sc = g[c] * rsqrtf(v + 1e-5f);
        scl[c] = sc;
        shf[c] = bt[c] - m * sc;
    }
}

// ---------------- fold BN into weights: W16 = bf16(W*scl), b' = c + W@shf --
__global__ __launch_bounds__(256) void foldw_kernel(
    const float* __restrict__ W, const float* __restrict__ scl,
    const float* __restrict__ shf, const float* __restrict__ bias,
    u16* __restrict__ W16, float* __restrict__ bout, int K, int nvalid)
{
    __shared__ float red[4];
    const int n = blockIdx.x, t = threadIdx.x;
    u16* o = W16 + (size_t)n * K;
    if (n >= nvalid) {
        for (int k = t; k < K; k += 256) o[k] = 0;
        if (t == 0) bout[n] = 0.f;
        return;
    }
    const float* w = W + (size_t)n * K;
    float part = 0.f;
    for (int k = t; k < K; k += 256) {
        float wv = w[k];
        float s = scl ? scl[k] : 1.f;
        float f = shf ? shf[k] : 0.f;
        o[k] = f2bf(wv * s);
        part += wv * f;
    }
    int lane = t & 63, wv_ = t >> 6;
#pragma unroll
    for (int off = 32; off > 0; off >>= 1) part += __shfl_down(part, off);
    if (lane == 0) red[wv_] = part;
    __syncthreads();
    if (t == 0)
        bout[n] = (bias ? bias[n] : 0.f) + red[0] + red[1] + red[2] + red[3];
}

// ---------------- bf16 MFMA GEMM, double-buffered --------------------------
// C = epi(A @ W^T + bias). 64x64 tile, BK=64, 4 waves (2x2 of 32x32).
// STATS: write per-block (64-row) column sum/sumsq of outputs to PART slice
//        blockIdx.y. ASRCF: tile == one GAT head; write a_src/a_tgt rows.
template<bool EPI, bool S32, bool S16, bool STATS, bool ASRCF>
__global__ __launch_bounds__(256) void mfma_gemm(
    const u16* __restrict__ A, const u16* __restrict__ W,
    const float* __restrict__ bias, float* __restrict__ C32,
    u16* __restrict__ C16, float* __restrict__ PART,
    const float* __restrict__ Wa, float* __restrict__ ASRC,
    float* __restrict__ ATGT, int M, int N, int K)
{
    __shared__ u16 As[2][4096];
    __shared__ u16 Bs[2][4096];
    __shared__ float ep1[2][64];   // STATS: scol | ASRCF: a_src halves
    __shared__ float ep2[2][64];   // STATS: qcol | ASRCF: a_tgt halves
    const int t = threadIdx.x;
    const int lane = t & 63, wv = t >> 6;
    const int wm = (wv >> 1) * 32, wn = (wv & 1) * 32;
    const int tile_m = blockIdx.y * 64, tile_n = blockIdx.x * 64;

    f32x4 acc[2][2];
#pragma unroll
    for (int i = 0; i < 2; ++i)
#pragma unroll
        for (int j = 0; j < 2; ++j)
#pragma unroll
            for (int e = 0; e < 4; ++e) acc[i][j][e] = 0.f;

    // staging geometry (pre-swizzled source, linear LDS dest; rule #21)
    int srow[2], soff[2];
#pragma unroll
    for (int i = 0; i < 2; ++i) {
        int f = i * 256 + t;
        srow[i] = f >> 3;
        soff[i] = ((f & 7) ^ (srow[i] & 7)) * 8;     // elements
    }
    const int wvoff = wv * 1024;                      // wave-uniform byte base
    const int frow_a0 = wm + (lane & 15);
    const int frow_b0 = wn + (lane & 15);
    const int fk = (lane >> 4) * 16;

    const int NT = K >> 6;
    int cur = 0;

#define STAGE(B, KT)                                                        \
    {                                                                        \
        _Pragma("unroll")                                                    \
        for (int i = 0; i < 2; ++i) {                                        \
            gload16(A + (size_t)(tile_m + srow[i]) * K + (KT) * 64 + soff[i],\
                    (char*)As[B] + wvoff + i * 4096);                        \
            gload16(W + (size_t)(tile_n + srow[i]) * K + (KT) * 64 + soff[i],\
                    (char*)Bs[B] + wvoff + i * 4096);                        \
        }                                                                    \
    }

    STAGE(0, 0);
    __syncthreads();
    for (int kt = 0; kt < NT; ++kt) {
        if (kt + 1 < NT) STAGE(cur ^ 1, kt + 1);      // loads fly under MFMA
        const char* baseA = (const char*)As[cur];
        const char* baseB = (const char*)Bs[cur];
#pragma unroll
        for (int kk = 0; kk < 2; ++kk) {
            bf16x8 a[2], b[2];
#pragma unroll
            for (int mi = 0; mi < 2; ++mi) {
                int r = frow_a0 + mi * 16;
                a[mi] = *(const bf16x8*)(baseA + r * 128 +
                        ((kk * 64 + fk) ^ ((r & 7) << 4)));
            }
#pragma unroll
            for (int ni = 0; ni < 2; ++ni) {
                int r = frow_b0 + ni * 16;
                b[ni] = *(const bf16x8*)(baseB + r * 128 +
                        ((kk * 64 + fk) ^ ((r & 7) << 4)));
            }
#pragma unroll
            for (int mi = 0; mi < 2; ++mi)
#pragma unroll
                for (int ni = 0; ni < 2; ++ni)
                    acc[mi][ni] = __builtin_amdgcn_mfma_f32_16x16x32_bf16(
                        a[mi], b[ni], acc[mi][ni], 0, 0, 0);
        }
        __syncthreads();   // vmcnt(0)+lgkmcnt(0)+barrier: next buf staged
        cur ^= 1;
    }
#undef STAGE

    // ---- epilogue: D col=lane&15, row=(lane>>4)*4+e (m89/m91) ----
    float st0 = 0.f, st1 = 0.f, sq0 = 0.f, sq1 = 0.f;
#pragma unroll
    for (int mi = 0; mi < 2; ++mi) {
#pragma unroll
        for (int ni = 0; ni < 2; ++ni) {
            int col = tile_n + wn + ni * 16 + (lane & 15);
            float bs = 0.f;
            if (EPI) bs = bias[col];
#pragma unroll
            for (int e = 0; e < 4; ++e) {
                int row = tile_m + wm + mi * 16 + ((lane >> 4) << 2) + e;
                float c = acc[mi][ni][e];
                if (EPI) c = gelu_f(c + bs);
                if (S32) C32[(size_t)row * N + col] = c;
                if (S16) C16[(size_t)row * N + col] = f2bf(c);
                if (STATS) {
                    if (ni == 0) { st0 += c; sq0 += c * c; }
                    else         { st1 += c; sq1 += c * c; }
                }
            }
        }
    }

    if (STATS) {
        // reduce over the wave's 32 rows (lanes sharing lane&15)
        float s0 = st0, s1 = st1, q0 = sq0, q1 = sq1;
        s0 += __shfl_xor(s0, 16); s0 += __shfl_xor(s0, 32);
        s1 += __shfl_xor(s1, 16); s1 += __shfl_xor(s1, 32);
        q0 += __shfl_xor(q0, 16); q0 += __shfl_xor(q0, 32);
        q1 += __shfl_xor(q1, 16); q1 += __shfl_xor(q1, 32);
        if (lane < 16) {
            ep1[wv >> 1][wn + lane] = s0;       ep2[wv >> 1][wn + lane] = q0;
            ep1[wv >> 1][wn + 16 + lane] = s1;  ep2[wv >> 1][wn + 16 + lane] = q1;
        }
        __syncthreads();
        if (t < 64) {
            float s = ep1[0][t] + ep1[1][t];
            float q = ep2[0][t] + ep2[1][t];
            PART[((size_t)blockIdx.y * N + tile_n + t) * 2 + 0] = s;
            PART[((size_t)blockIdx.y * N + tile_n + t) * 2 + 1] = q;
        }
    }

    if (ASRCF) {
        // tile == head blockIdx.x: a_src[r] = sum_d xh[r,d]*Wa[d] (d in tile)
        const int cl = lane & 15;
        float ws0 = Wa[wn + cl],      ws1 = Wa[wn + 16 + cl];
        float wt0 = Wa[64 + wn + cl], wt1 = Wa[64 + wn + 16 + cl];
#pragma unroll
        for (int mi = 0; mi < 2; ++mi)
#pragma unroll
            for (int e = 0; e < 4; ++e) {
                float vs = acc[mi][0][e] * ws0 + acc[mi][1][e] * ws1;
                float vt = acc[mi][0][e] * wt0 + acc[mi][1][e] * wt1;
#pragma unroll
                for (int off = 1; off < 16; off <<= 1) {
                    vs += __shfl_xor(vs, off);
                    vt += __shfl_xor(vt, off);
                }
                if (cl == 0) {
                    int row = wm + mi * 16 + ((lane >> 4) << 2) + e;
                    ep1[wv & 1][row] = vs;
                    ep2[wv & 1][row] = vt;
                }
            }
        __syncthreads();
        if (t < 64) {
            int h = blockIdx.x;
            ASRC[(size_t)(tile_m + t) * 4 + h] = ep1[0][t] + ep1[1][t];
            ATGT[(size_t)(tile_m + t) * 4 + h] = ep2[0][t] + ep2[1][t];
        }
    }
}

// ---------------- gathered logits GEMM (double-buffered) -------------------
__global__ __launch_bounds__(256) void logits_mfma(
    const u16* __restrict__ xf16, const int* __restrict__ idxs,
    const u16* __restrict__ WlP, const float* __restrict__ clP,
    float* __restrict__ out)
{
    __shared__ u16 As[2][4096];
    __shared__ u16 Bs[2][4096];
    const int t = threadIdx.x;
    const int lane = t & 63, wv = t >> 6;
    const int wm = (wv >> 1) * 32, wn = (wv & 1) * 32;
    const int tile_m = blockIdx.x * 64;

    f32x4 acc[2][2];
#pragma unroll
    for (int i = 0; i < 2; ++i)
#pragma unroll
        for (int j = 0; j < 2; ++j)
#pragma unroll
            for (int e = 0; e < 4; ++e) acc[i][j][e] = 0.f;

    int srow[2], soff[2], gr[2];
#pragma unroll
    for (int i = 0; i < 2; ++i) {
        int f = i * 256 + t;
        srow[i] = f >> 3;
        soff[i] = ((f & 7) ^ (srow[i] & 7)) * 8;
        gr[i] = idxs[tile_m + srow[i]];
    }
    const int wvoff = wv * 1024;
    const int frow_a0 = wm + (lane & 15);
    const int frow_b0 = wn + (lane & 15);
    const int fk = (lane >> 4) * 16;

#define LSTAGE(B, KT)                                                       \
    {                                                                        \
        _Pragma("unroll")                                                    \
        for (int i = 0; i < 2; ++i) {                                        \
            gload16(xf16 + (size_t)gr[i] * 256 + (KT) * 64 + soff[i],        \
                    (char*)As[B] + wvoff + i * 4096);                        \
            gload16(WlP + (size_t)srow[i] * 256 + (KT) * 64 + soff[i],       \
                    (char*)Bs[B] + wvoff + i * 4096);                        \
        }                                                                    \
    }

    int cur = 0;
    LSTAGE(0, 0);
    __syncthreads();
#pragma unroll
    for (int kt = 0; kt < 4; ++kt) {             // K = 256
        if (kt + 1 < 4) LSTAGE(cur ^ 1, kt + 1);
        const char* baseA = (const char*)As[cur];
        const char* baseB = (const char*)Bs[cur];
#pragma unroll
        for (int kk = 0; kk < 2; ++kk) {
            bf16x8 a[2], b[2];
#pragma unroll
            for (int mi = 0; mi < 2; ++mi) {
                int r = frow_a0 + mi * 16;
                a[mi] = *(const bf16x8*)(baseA + r * 128 +
                        ((kk * 64 + fk) ^ ((r & 7) << 4)));
            }
#pragma unroll
            for (int ni = 0; ni < 2; ++ni) {
                int r = frow_b0 + ni * 16;
                b[ni] = *(const bf16x8*)(baseB + r * 128 +
                        ((kk * 64 + fk) ^ ((r & 7) << 4)));
            }
#pragma unroll
            for (int mi = 0; mi < 2; ++mi)
#pragma unroll
                for (int ni = 0; ni < 2; ++ni)
                    acc[mi][ni] = __builtin_amdgcn_mfma_f32_16x16x32_bf16(
                        a[mi], b[ni], acc[mi][ni], 0, 0, 0);
        }
        __syncthreads();
        cur ^= 1;
    }
#undef LSTAGE

#pragma unroll
    for (int mi = 0; mi < 2; ++mi) {
#pragma unroll
        for (int ni = 0; ni < 2; ++ni) {
            int col = wn + ni * 16 + (lane & 15);
            if (col < 40) {
                float bs = clP[col];
#pragma unroll
                for (int e = 0; e < 4; ++e) {
                    int row = tile_m + wm + mi * 16 + ((lane >> 4) << 2) + e;
                    out[(size_t)row * 40 + col] = acc[mi][ni][e] + bs;
                }
            }
        }
    }
}

// ---------------- adjacency -> neighbor lists (block per row) --------------
__global__ __launch_bounds__(256) void build_nbr_kernel(
    const unsigned char* __restrict__ adj, int* __restrict__ nbr,
    int* __restrict__ deg)
{
    __shared__ int lists[4][CAP];
    __shared__ int cnts[4];
    __shared__ int sflag;
    const int i = blockIdx.x;
    const int t = threadIdx.x;
    const int wv = t >> 6, lane = t & 63;

    if (wv == 0) {
        bool a = adj[(size_t)lane * 4097] != 0;
        bool b = ((const unsigned int*)adj)[(size_t)lane * 4097] != 0;
        unsigned long long mA = __ballot(a);
        unsigned long long mB = __ballot(b);
        if (lane == 0) sflag = (__popcll(mA) >= __popcll(mB)) ? 0 : 1;
    }
    __syncthreads();
    int cnt = 0;

    if (sflag == 1) {
        const uint4* row = (const uint4*)((const unsigned int*)adj + (size_t)i * NNODES);
#pragma unroll
        for (int w = 0; w < 4; ++w) {
            uint4 v = row[w * 256 + t];
            unsigned wd[4] = {v.x, v.y, v.z, v.w};
#pragma unroll
            for (int j = 0; j < 4; ++j) {
                bool on = wd[j] != 0;
                unsigned long long m = __ballot(on);
                int pre = __popcll(m & ((1ull << lane) - 1ull));
                if (on && cnt + pre < CAP)
                    lists[wv][cnt + pre] = (w * 256 + t) * 4 + j;
                cnt += __popcll(m);
            }
        }
    } else {
        uint4 v = ((const uint4*)(adj + (size_t)i * NNODES))[t];
        unsigned wd[4] = {v.x, v.y, v.z, v.w};
#pragma unroll
        for (int j = 0; j < 4; ++j)
#pragma unroll
            for (int b = 0; b < 4; ++b) {
                bool on = ((wd[j] >> (8 * b)) & 0xffu) != 0;
                unsigned long long m = __ballot(on);
                int pre = __popcll(m & ((1ull << lane) - 1ull));
                if (on && cnt + pre < CAP)
                    lists[wv][cnt + pre] = t * 16 + j * 4 + b;
                cnt += __popcll(m);
            }
    }
    if (lane == 0) cnts[wv] = cnt < CAP ? cnt : CAP;
    __syncthreads();
    int offw = 0;
#pragma unroll
    for (int w2 = 0; w2 < 4; ++w2) if (w2 < wv) offw += cnts[w2];
    int myc = cnts[wv];
    for (int k = lane; k < myc; k += 64) {
        int pos = offw + k;
        if (pos < CAP) nbr[(size_t)i * CAP + pos] = lists[wv][k];
    }
    if (t == 0) {
        int tot = cnts[0] + cnts[1] + cnts[2] + cnts[3];
        deg[i] = tot < CAP ? tot : CAP;
    }
}

// ---------------- attention + residual + LayerNorm (bf16 xh gather) --------
__global__ __launch_bounds__(256) void attn_ln_kernel(
    const u16* __restrict__ xh, const float* __restrict__ x0,
    const float* __restrict__ asrc, const float* __restrict__ atgt,
    const int* __restrict__ nbr, const int* __restrict__ deg_,
    const float* __restrict__ ln_g, const float* __restrict__ ln_b,
    float* __restrict__ xln, u16* __restrict__ xln16)
{
    __shared__ float att[CAP * 4];
    __shared__ int nb[CAP];
    __shared__ float red[8];
    const int i = blockIdx.x;
    const int t = threadIdx.x;
    const int dg = deg_[i];

    for (int k = t; k < dg; k += 256) nb[k] = nbr[(size_t)i * CAP + k];
    __syncthreads();

    for (int idx = t; idx < dg * 4; idx += 256) {
        int k = idx >> 2, h = idx & 3;
        float e = asrc[nb[k] * 4 + h] + atgt[i * 4 + h];
        att[idx] = e > 0.f ? e : 0.2f * e;
    }
    __syncthreads();

    const int wv = t >> 6, lane = t & 63;
    {
        const int h = wv;
        float m = -1e30f;
        for (int k = lane; k < dg; k += 64) m = fmaxf(m, att[k * 4 + h]);
#pragma unroll
        for (int off = 32; off > 0; off >>= 1) m = fmaxf(m, __shfl_xor(m, off));
        float s = 0.f;
        for (int k = lane; k < dg; k += 64) s += expf(att[k * 4 + h] - m);
#pragma unroll
        for (int off = 32; off > 0; off >>= 1) s += __shfl_xor(s, off);
        float inv = 1.0f / s;
        for (int k = lane; k < dg; k += 64)
            att[k * 4 + h] = expf(att[k * 4 + h] - m) * inv;
    }
    __syncthreads();

    const int h = t >> 6;
    float acc = 0.f;
    int k = 0;
    for (; k + 4 <= dg; k += 4) {
        float a0 = att[(k + 0) * 4 + h], v0 = bf2f(xh[(size_t)nb[k + 0] * 256 + t]);
        float a1 = att[(k + 1) * 4 + h], v1 = bf2f(xh[(size_t)nb[k + 1] * 256 + t]);
        float a2 = att[(k + 2) * 4 + h], v2 = bf2f(xh[(size_t)nb[k + 2] * 256 + t]);
        float a3 = att[(k + 3) * 4 + h], v3 = bf2f(xh[(size_t)nb[k + 3] * 256 + t]);
        acc = fmaf(a0, v0, acc); acc = fmaf(a1, v1, acc);
        acc = fmaf(a2, v2, acc); acc = fmaf(a3, v3, acc);
    }
    for (; k < dg; ++k)
        acc = fmaf(att[k * 4 + h], bf2f(xh[(size_t)nb[k] * 256 + t]), acc);

    float v = x0[(size_t)i * 256 + t] + acc;
    float s = v, q = v * v;
#pragma unroll
    for (int off = 32; off > 0; off >>= 1) {
        s += __shfl_xor(s, off);
        q += __shfl_xor(q, off);
    }
    if (lane == 0) { red[wv] = s; red[4 + wv] = q; }
    __syncthreads();
    float S = red[0] + red[1] + red[2] + red[3];
    float Q = red[4] + red[5] + red[6] + red[7];
    float mu = S * (1.0f / 256.0f);
    float var = Q * (1.0f / 256.0f) - mu * mu;
    float y = (v - mu) * rsqrtf(var + 1e-5f) * ln_g[t] + ln_b[t];
    xln[(size_t)i * 256 + t] = y;
    xln16[(size_t)i * 256 + t] = f2bf(y);
}

// ---------------------------------------------------------------------------
extern "C" void kernel_launch(void* const* d_in, const int* in_sizes, int n_in,
                              void* d_out, int out_size, void* d_ws, size_t ws_size,
                              hipStream_t stream)
{
    const float* nf      = (const float*)d_in[0];
    const float* pre_g1  = (const float*)d_in[1];
    const float* pre_b1  = (const float*)d_in[2];
    const float* pre_W1  = (const float*)d_in[3];
    const float* pre_c1  = (const float*)d_in[4];
    const float* pre_g2  = (const float*)d_in[5];
    const float* pre_b2  = (const float*)d_in[6];
    const float* pre_W2  = (const float*)d_in[7];
    const float* pre_c2  = (const float*)d_in[8];
    const float* Wp      = (const float*)d_in[9];
    const float* Wa      = (const float*)d_in[10];
    const float* ln_g    = (const float*)d_in[11];
    const float* ln_b    = (const float*)d_in[12];
    const float* post_g1 = (const float*)d_in[13];
    const float* post_b1 = (const float*)d_in[14];
    const float* post_W1 = (const float*)d_in[15];
    const float* post_c1 = (const float*)d_in[16];
    const float* post_g2 = (const float*)d_in[17];
    const float* post_b2 = (const float*)d_in[18];
    const float* post_W2 = (const float*)d_in[19];
    const float* post_c2 = (const float*)d_in[20];
    const float* Wl      = (const float*)d_in[21];
    const float* cl      = (const float*)d_in[22];
    const unsigned char* adj = (const unsigned char*)d_in[23];
    const int* idxs      = (const int*)d_in[24];
    float* out = (float*)d_out;

    size_t off = 0;
    char* base = (char*)d_ws;
    auto carve = [&](size_t bytes) {
        void* p = base + off;
        off += (bytes + 255) & ~(size_t)255;
        return p;
    };
    u16*   Y16   = (u16*)  carve((size_t)4096 * 1024 * 2);
    u16*   NF16  = (u16*)  carve((size_t)4096 * 512 * 2);
    float* X032  = (float*)carve((size_t)4096 * 256 * 4);
    u16*   X016  = (u16*)  carve((size_t)4096 * 256 * 2);
    u16*   XH16  = (u16*)  carve((size_t)4096 * 256 * 2);
    float* XLN32 = (float*)carve((size_t)4096 * 256 * 4);
    u16*   XLN16 = (u16*)  carve((size_t)4096 * 256 * 2);
    u16*   XF16  = (u16*)  carve((size_t)4096 * 256 * 2);
    u16*   W1_16 = (u16*)  carve((size_t)1024 * 512 * 2);
    u16*   W2_16 = (u16*)  carve((size_t)256 * 1024 * 2);
    u16*   Wp16  = (u16*)  carve((size_t)256 * 256 * 2);
    u16*   W3_16 = (u16*)  carve((size_t)1024 * 256 * 2);
    u16*   W4_16 = (u16*)  carve((size_t)256 * 1024 * 2);
    u16*   WlP16 = (u16*)  carve((size_t)64 * 256 * 2);
    float* B1    = (float*)carve(1024 * 4);
    float* B2    = (float*)carve(256 * 4);
    float* BP    = (float*)carve(256 * 4);
    float* B3    = (float*)carve(1024 * 4);
    float* B4    = (float*)carve(256 * 4);
    float* CLP   = (float*)carve(64 * 4);
    int*   NBR   = (int*)  carve((size_t)4096 * CAP * 4);
    int*   DEG   = (int*)  carve((size_t)4096 * 4);
    float* ASRC  = (float*)carve((size_t)4096 * 4 * 4);
    float* ATGT  = (float*)carve((size_t)4096 * 4 * 4);
    float* PART  = (float*)carve((size_t)256 * 1024 * 2 * 4);
    float* SCL1  = (float*)carve(512 * 4);
    float* SHF1  = (float*)carve(512 * 4);
    float* SCL2  = (float*)carve(1024 * 4);
    float* SHF2  = (float*)carve(1024 * 4);
    float* SCL3  = (float*)carve(256 * 4);
    float* SHF3  = (float*)carve(256 * 4);
    float* SCL4  = (float*)carve(1024 * 4);
    float* SHF4  = (float*)carve(1024 * 4);
    (void)ws_size; (void)n_in; (void)in_sizes; (void)out_size;

    const int NB = 128, RPB = 4096 / 128;

    // neighbor lists early (independent of FFN chain); probe inlined
    build_nbr_kernel<<<4096, 256, 0, stream>>>(adj, NBR, DEG);

    // --- stage 1: BN1 stats on nf (+bf16 cvt), fold, GEMM1 -> Y16 + PART
    colstats_partial<2, true><<<NB, 256, 0, stream>>>(nf, PART, NF16, RPB);
    colstats_final<<<512 / 16, 256, 0, stream>>>(PART, pre_g1, pre_b1, SCL1, SHF1, NB, 512);
    foldw_kernel<<<1024, 256, 0, stream>>>(pre_W1, SCL1, SHF1, pre_c1, W1_16, B1, 512, 1024);
    mfma_gemm<true, false, true, true, false><<<dim3(16, 64), 256, 0, stream>>>(
        NF16, W1_16, B1, nullptr, Y16, PART, nullptr, nullptr, nullptr,
        4096, 1024, 512);

    // --- stage 2: BN2 (from GEMM1-fused stats), fold, GEMM2 -> X032 + X016
    colstats_final<<<1024 / 16, 256, 0, stream>>>(PART, pre_g2, pre_b2, SCL2, SHF2, 64, 1024);
    foldw_kernel<<<256, 256, 0, stream>>>(pre_W2, SCL2, SHF2, pre_c2, W2_16, B2, 1024, 256);
    mfma_gemm<true, true, true, false, false><<<dim3(4, 64), 256, 0, stream>>>(
        Y16, W2_16, B2, X032, X016, nullptr, nullptr, nullptr, nullptr,
        4096, 256, 1024);

    // --- stage 3: GEMM3 -> XH16 + fused a_src/a_tgt
    foldw_kernel<<<256, 256, 0, stream>>>(Wp, nullptr, nullptr, nullptr, Wp16, BP, 256, 256);
    mfma_gemm<false, false, true, false, true><<<dim3(4, 64), 256, 0, stream>>>(
        X016, Wp16, nullptr, nullptr, XH16, nullptr, Wa, ASRC, ATGT,
        4096, 256, 256);

    // --- attention + residual + LayerNorm
    attn_ln_kernel<<<4096, 256, 0, stream>>>(XH16, X032, ASRC, ATGT, NBR, DEG,
                                             ln_g, ln_b, XLN32, XLN16);

    // --- stage 4: BN3 stats on XLN, fold, GEMM4 -> Y16 + PART
    colstats_partial<1, false><<<NB, 256, 0, stream>>>(XLN32, PART, nullptr, RPB);
    colstats_final<<<256 / 16, 256, 0, stream>>>(PART, post_g1, post_b1, SCL3, SHF3, NB, 256);
    foldw_kernel<<<1024, 256, 0, stream>>>(post_W1, SCL3, SHF3, post_c1, W3_16, B3, 256, 1024);
    mfma_gemm<true, false, true, true, false><<<dim3(16, 64), 256, 0, stream>>>(
        XLN16, W3_16, B3, nullptr, Y16, PART, nullptr, nullptr, nullptr,
        4096, 1024, 256);

    // --- stage 5: BN4 (from GEMM4-fused stats), fold, GEMM5 -> XF16
    colstats_final<<<1024 / 16, 256, 0, stream>>>(PART, post_g2, post_b2, SCL4, SHF4, 64, 1024);
    foldw_kernel<<<256, 256, 0, stream>>>(post_W2, SCL4, SHF4, post_c2, W4_16, B4, 1024, 256);
    mfma_gemm<true, false, true, false, false><<<dim3(4, 64), 256, 0, stream>>>(
        Y16, W4_16, B4, nullptr, XF16, nullptr, nullptr, nullptr, nullptr,
        4096, 256, 1024);

    // --- logits: fold Wl (pad 40->64) + gathered MFMA GEMM
    foldw_kernel<<<64, 256, 0, stream>>>(Wl, nullptr, nullptr, cl, WlP16, CLP, 256, 40);
    logits_mfma<<<128, 256, 0, stream>>>(XF16, idxs, WlP16, CLP, out);
}